// Round 1
// baseline (246.562 us; speedup 1.0000x reference)
//
#include <hip/hip_runtime.h>
#include <hip/hip_bf16.h>

#define B_   64
#define N_   2304
#define D_   8
#define J_   32
#define L_   16
#define NC_  18      // n-chunks for step kernel
#define NPB_ 128     // n per block (NC_*NPB_ == N_)
#define EPS_ 1e-7f

// ---------------- Ws[n,j,l] = sum_k W[n,j,k,l] ----------------
// One float4 output per thread. W flat: n*4096 + j*128 + k*16 + l.
__global__ __launch_bounds__(256) void reduce_w_kernel(const float* __restrict__ W,
                                                       float* __restrict__ Ws) {
    int o4 = blockIdx.x * 256 + threadIdx.x;          // 0 .. N*J*L/4-1 (294912)
    if (o4 >= (N_ * J_ * L_) / 4) return;
    int n = o4 >> 7;                                  // 128 float4 per n
    int r = o4 & 127;                                 // j*4 + l4
    const float4* base = (const float4*)W + n * 1024 + (r >> 2) * 32 + (r & 3);
    float4 s = make_float4(0.f, 0.f, 0.f, 0.f);
#pragma unroll
    for (int k = 0; k < D_; ++k) {
        float4 t = base[k * 4];
        s.x += t.x; s.y += t.y; s.z += t.z; s.w += t.w;
    }
    ((float4*)Ws)[o4] = s;
}

// ---------------- xs[b,n] = sum_i x[b,n,i] ----------------
__global__ __launch_bounds__(256) void reduce_x_kernel(const float* __restrict__ x,
                                                       float* __restrict__ xs) {
    int o = blockIdx.x * 256 + threadIdx.x;           // 0 .. B*N-1 (147456)
    if (o >= B_ * N_) return;
    const float4* p = (const float4*)x + o * 2;
    float4 a = p[0], c = p[1];
    xs[o] = a.x + a.y + a.z + a.w + c.x + c.y + c.z + c.w;
}

// ---------------- routing step ----------------
// grid = (NC_, B_), block = 256 (4 waves). Each wave owns n = chunk*NPB_ + nn,
// nn = wave, wave+4, ... Each lane accumulates s over flat jl range
// [lane*8, lane*8+8) in registers; waves reduced via LDS at the end.
__global__ __launch_bounds__(256) void step_kernel(const float* __restrict__ Ws,
                                                   const float* __restrict__ xs,
                                                   const float* __restrict__ v0,
                                                   const float* __restrict__ v1,
                                                   int nprev,
                                                   float* __restrict__ s_part) {
    const int b     = blockIdx.y;
    const int chunk = blockIdx.x;
    const int tid   = threadIdx.x;
    const int wave  = tid >> 6;
    const int lane  = tid & 63;
    const int jme   = lane & 31;        // j this lane computes softmax for
    const int jl0   = lane * 8;         // flat jl base this lane accumulates

    const float* vp0 = v0 + b * (J_ * L_);
    const float* vp1 = v1 + b * (J_ * L_);

    float acc[8];
#pragma unroll
    for (int q = 0; q < 8; ++q) acc[q] = 0.f;

    for (int nn = wave; nn < NPB_; nn += 4) {
        const int n = chunk * NPB_ + nn;
        const float* wsn = Ws + n * (J_ * L_);
        const float xsv = xs[b * N_ + n];

        // ---- logits (recomputed from v history) ----
        float logit = 0.f;
        if (nprev > 0) {
            const float4* wr = (const float4*)(wsn + jme * L_);
            float4 wreg[4];
#pragma unroll
            for (int q = 0; q < 4; ++q) wreg[q] = wr[q];
            const float4* vr0 = (const float4*)(vp0 + jme * L_);
            float d = 0.f;
#pragma unroll
            for (int q = 0; q < 4; ++q) {
                float4 vv = vr0[q];
                d += wreg[q].x * vv.x + wreg[q].y * vv.y + wreg[q].z * vv.z + wreg[q].w * vv.w;
            }
            logit = d;
            if (nprev > 1) {
                const float4* vr1 = (const float4*)(vp1 + jme * L_);
                float d1 = 0.f;
#pragma unroll
                for (int q = 0; q < 4; ++q) {
                    float4 vv = vr1[q];
                    d1 += wreg[q].x * vv.x + wreg[q].y * vv.y + wreg[q].z * vv.z + wreg[q].w * vv.w;
                }
                logit += d1;
            }
            logit *= xsv;
        }

        // ---- softmax over j=0..31 (both 32-lane halves hold duplicates) ----
        float m = logit;
#pragma unroll
        for (int off = 16; off >= 1; off >>= 1) m = fmaxf(m, __shfl_xor(m, off));
        float e = __expf(logit - m);
        float ssum = e;
#pragma unroll
        for (int off = 16; off >= 1; off >>= 1) ssum += __shfl_xor(ssum, off);
        float w = (e / ssum) * xsv;     // c[j] * xs

        // weight for the j my accumulation range belongs to (j = lane>>1)
        float wj = __shfl(w, lane >> 1);

        // ---- accumulate s[jl0..jl0+8) += wj * Ws[n, jl0..jl0+8) ----
        const float4* wsv = (const float4*)(wsn + jl0);
        float4 a0 = wsv[0], a1 = wsv[1];
        acc[0] += wj * a0.x; acc[1] += wj * a0.y; acc[2] += wj * a0.z; acc[3] += wj * a0.w;
        acc[4] += wj * a1.x; acc[5] += wj * a1.y; acc[6] += wj * a1.z; acc[7] += wj * a1.w;
    }

    // ---- reduce the 4 waves' accumulators ----
    __shared__ float sred[4][J_ * L_];
#pragma unroll
    for (int q = 0; q < 8; ++q) sred[wave][jl0 + q] = acc[q];
    __syncthreads();
    for (int i = tid; i < J_ * L_; i += 256) {
        float s = sred[0][i] + sred[1][i] + sred[2][i] + sred[3][i];
        s_part[(b * NC_ + chunk) * (J_ * L_) + i] = s;
    }
}

// ---------------- reduce partials + squash ----------------
// grid = B_, block = 512 (thread = flat jl)
__global__ __launch_bounds__(512) void reduce_squash_kernel(const float* __restrict__ s_part,
                                                            float* __restrict__ vout) {
    const int b = blockIdx.x;
    const int tid = threadIdx.x;          // j*16 + l
    float s = 0.f;
#pragma unroll
    for (int c = 0; c < NC_; ++c) s += s_part[(b * NC_ + c) * (J_ * L_) + tid];
    float sq = s * s;
#pragma unroll
    for (int off = 8; off >= 1; off >>= 1) sq += __shfl_xor(sq, off);
    float scale = sq / (1.f + sq) / sqrtf(sq + EPS_);
    vout[b * (J_ * L_) + tid] = scale * s;
}

extern "C" void kernel_launch(void* const* d_in, const int* in_sizes, int n_in,
                              void* d_out, int out_size, void* d_ws, size_t ws_size,
                              hipStream_t stream) {
    const float* x = (const float*)d_in[0];   // [B, N, D]
    const float* W = (const float*)d_in[1];   // [N, J, D, L]
    float* out = (float*)d_out;               // [B, J, L]

    float* ws    = (float*)d_ws;
    float* Ws    = ws;                         // N*J*L      = 1179648
    float* xs    = Ws + (size_t)N_ * J_ * L_;  // B*N        = 147456
    float* v0    = xs + (size_t)B_ * N_;       // B*J*L      = 32768
    float* v1    = v0 + (size_t)B_ * J_ * L_;  // B*J*L      = 32768
    float* s_part = v1 + (size_t)B_ * J_ * L_; // B*NC*J*L   = 589824
    // total ~7.93 MB of workspace

    reduce_w_kernel<<<(N_ * J_ * L_ / 4 + 255) / 256, 256, 0, stream>>>(W, Ws);
    reduce_x_kernel<<<(B_ * N_ + 255) / 256, 256, 0, stream>>>(x, xs);

    dim3 sg(NC_, B_);
    // t = 0
    step_kernel<<<sg, 256, 0, stream>>>(Ws, xs, v0, v1, 0, s_part);
    reduce_squash_kernel<<<B_, 512, 0, stream>>>(s_part, v0);
    // t = 1
    step_kernel<<<sg, 256, 0, stream>>>(Ws, xs, v0, v1, 1, s_part);
    reduce_squash_kernel<<<B_, 512, 0, stream>>>(s_part, v1);
    // t = 2
    step_kernel<<<sg, 256, 0, stream>>>(Ws, xs, v0, v1, 2, s_part);
    reduce_squash_kernel<<<B_, 512, 0, stream>>>(s_part, out);
}

// Round 2
// 117.534 us; speedup vs baseline: 2.0978x; 2.0978x over previous
//
#include <hip/hip_runtime.h>
#include <hip/hip_bf16.h>

#define B_   64
#define N_   2304
#define D_   8
#define J_   32
#define L_   16
#define EPS_ 1e-7f

// workspace layouts (all float):
//   Ws  [n][j][l]       N*J*L   (4.72 MB)  sum_k W
//   xsT [n][b]          N*B     (0.59 MB)  sum_i x, transposed
//   u   [j][b][l]       J*B*L   (0.13 MB)  cumulative sum of v_t
//   wgt [j][n][b]       J*N*B   (18.9 MB)  softmax_j(logit)*xs
//   p   [j][kc][b][l]   J*64*B*L (8.4 MB)  s-partials over 64 n-chunks

// ---------------- Ws[n,j,l] = sum_k W[n,j,k,l] ----------------
__global__ __launch_bounds__(256) void reduce_w_kernel(const float* __restrict__ W,
                                                       float* __restrict__ Ws) {
    int o4 = blockIdx.x * 256 + threadIdx.x;          // float4 index
    if (o4 >= (N_ * J_ * L_) / 4) return;
    int n = o4 >> 7;
    int r = o4 & 127;                                 // j*4 + l4
    const float4* base = (const float4*)W + n * 1024 + (r >> 2) * 32 + (r & 3);
    float4 s = make_float4(0.f, 0.f, 0.f, 0.f);
#pragma unroll
    for (int k = 0; k < D_; ++k) {
        float4 t = base[k * 4];
        s.x += t.x; s.y += t.y; s.z += t.z; s.w += t.w;
    }
    ((float4*)Ws)[o4] = s;
}

// ---------------- xsT[n][b] = sum_i x[b,n,i] (transposed) ----------------
// grid 576, block 256: block covers 4 n x 64 b.
__global__ __launch_bounds__(256) void reduce_x_kernel(const float* __restrict__ x,
                                                       float* __restrict__ xsT) {
    const int t  = threadIdx.x;
    const int b  = t >> 2;
    const int nl = t & 3;
    const int n0 = blockIdx.x * 4;
    const float4* p = (const float4*)(x + ((size_t)b * N_ + n0 + nl) * D_);
    float4 a = p[0], c = p[1];
    float s = a.x + a.y + a.z + a.w + c.x + c.y + c.z + c.w;
    __shared__ float tr[4][64];
    tr[nl][b] = s;
    __syncthreads();
    const int nn = t >> 6, lb = t & 63;
    xsT[(n0 + nn) * B_ + lb] = tr[nn][lb];
}

// ---------------- wgt[j][n][b] = softmax_j(xs * sum_l Ws*u) * xs ----------------
// grid 576, block 256 (4 waves). wave <-> n, lane <-> b. Softmax fully in-lane.
__global__ __launch_bounds__(256) void wgt_kernel(const float* __restrict__ Ws,
                                                  const float* __restrict__ xsT,
                                                  const float* __restrict__ u,
                                                  float* __restrict__ wgt,
                                                  int first) {
    const int wave = threadIdx.x >> 6;
    const int lane = threadIdx.x & 63;                 // = b
    const int n = __builtin_amdgcn_readfirstlane(blockIdx.x * 4 + wave);
    const float xsv = xsT[n * B_ + lane];

    if (first) {
        const float c = xsv * (1.0f / 32.0f);
#pragma unroll
        for (int j = 0; j < J_; ++j)
            wgt[((size_t)j * N_ + n) * B_ + lane] = c;
        return;
    }

    float lg[J_];
#pragma unroll
    for (int j = 0; j < J_; ++j) {
        const float4* up = (const float4*)(u + ((size_t)j * B_ + lane) * L_);
        const float*  wp = Ws + ((size_t)n * J_ + j) * L_;   // wave-uniform -> s_load
        float4 u0 = up[0], u1 = up[1], u2 = up[2], u3 = up[3];
        float g = wp[0]  * u0.x + wp[1]  * u0.y + wp[2]  * u0.z + wp[3]  * u0.w
                + wp[4]  * u1.x + wp[5]  * u1.y + wp[6]  * u1.z + wp[7]  * u1.w
                + wp[8]  * u2.x + wp[9]  * u2.y + wp[10] * u2.z + wp[11] * u2.w
                + wp[12] * u3.x + wp[13] * u3.y + wp[14] * u3.z + wp[15] * u3.w;
        lg[j] = g * xsv;
    }
    // in-lane softmax over 32 registers (no cross-lane ops)
    float m = lg[0];
#pragma unroll
    for (int j = 1; j < J_; ++j) m = fmaxf(m, lg[j]);
    float sum = 0.f;
#pragma unroll
    for (int j = 0; j < J_; ++j) { lg[j] = __expf(lg[j] - m); sum += lg[j]; }
    const float sc = xsv / sum;
#pragma unroll
    for (int j = 0; j < J_; ++j)
        wgt[((size_t)j * N_ + n) * B_ + lane] = lg[j] * sc;
}

// ---------------- p[j][kc][b][l] = sum_{n in chunk} wgt[j][n][b] * Ws[n][j][l] ----------------
// grid (8, 64), block 256. wave <-> j (blockIdx.x*4+wave), lane <-> b, kc = blockIdx.y (36 n each).
__global__ __launch_bounds__(256) void acc_kernel(const float* __restrict__ Ws,
                                                  const float* __restrict__ wgt,
                                                  float* __restrict__ p) {
    const int wave = threadIdx.x >> 6;
    const int lane = threadIdx.x & 63;                 // = b
    const int j  = __builtin_amdgcn_readfirstlane(blockIdx.x * 4 + wave);
    const int kc = blockIdx.y;
    const int n0 = kc * 36;

    float acc[L_];
#pragma unroll
    for (int l = 0; l < L_; ++l) acc[l] = 0.f;

    for (int nn = 0; nn < 36; ++nn) {
        const int n = n0 + nn;
        const float w = wgt[((size_t)j * N_ + n) * B_ + lane];     // coalesced
        const float* wp = Ws + ((size_t)n * J_ + j) * L_;          // uniform -> s_load
#pragma unroll
        for (int l = 0; l < L_; ++l) acc[l] += w * wp[l];
    }

    float* pp = p + (((size_t)j * 64 + kc) * B_ + lane) * L_;
#pragma unroll
    for (int l4 = 0; l4 < 4; ++l4)
        ((float4*)pp)[l4] = make_float4(acc[l4 * 4 + 0], acc[l4 * 4 + 1],
                                        acc[l4 * 4 + 2], acc[l4 * 4 + 3]);
}

// ---------------- reduce partials + squash; update u / write out ----------------
// grid (32, 4), block 256: thread = b_local*16 + l. mode: 0 u=v, 1 u+=v, 2 write out.
__global__ __launch_bounds__(256) void squash_kernel(const float* __restrict__ p,
                                                     float* __restrict__ u,
                                                     float* __restrict__ out,
                                                     int mode) {
    const int j  = blockIdx.x;
    const int bq = blockIdx.y;
    const int t  = threadIdx.x;
    const int b  = bq * 16 + (t >> 4);
    const int l  = t & 15;

    const float* pp = p + (size_t)j * 64 * (B_ * L_) + bq * 256 + t;
    float s = 0.f;
#pragma unroll
    for (int kc = 0; kc < 64; ++kc) s += pp[(size_t)kc * (B_ * L_)];

    float sq = s * s;
#pragma unroll
    for (int off = 8; off >= 1; off >>= 1) sq += __shfl_xor(sq, off);
    const float scale = sq / (1.f + sq) / sqrtf(sq + EPS_);
    const float v = scale * s;

    if (mode == 0)      u[((size_t)j * B_ + b) * L_ + l]  = v;
    else if (mode == 1) u[((size_t)j * B_ + b) * L_ + l] += v;
    else                out[((size_t)b * J_ + j) * L_ + l] = v;
}

extern "C" void kernel_launch(void* const* d_in, const int* in_sizes, int n_in,
                              void* d_out, int out_size, void* d_ws, size_t ws_size,
                              hipStream_t stream) {
    const float* x = (const float*)d_in[0];   // [B, N, D]
    const float* W = (const float*)d_in[1];   // [N, J, D, L]
    float* out = (float*)d_out;               // [B, J, L]

    float* ws  = (float*)d_ws;
    float* Ws  = ws;                                    // N*J*L
    float* xsT = Ws  + (size_t)N_ * J_ * L_;            // N*B
    float* u   = xsT + (size_t)N_ * B_;                 // J*B*L
    float* wgt = u   + (size_t)J_ * B_ * L_;            // J*N*B
    float* p   = wgt + (size_t)J_ * N_ * B_;            // J*64*B*L

    reduce_w_kernel<<<(N_ * J_ * L_ / 4 + 255) / 256, 256, 0, stream>>>(W, Ws);
    reduce_x_kernel<<<N_ / 4, 256, 0, stream>>>(x, xsT);

    for (int t = 0; t < 3; ++t) {
        wgt_kernel<<<N_ / 4, 256, 0, stream>>>(Ws, xsT, u, wgt, t == 0 ? 1 : 0);
        acc_kernel<<<dim3(8, 64), 256, 0, stream>>>(Ws, wgt, p);
        squash_kernel<<<dim3(32, 4), 256, 0, stream>>>(p, u, out, t == 0 ? 0 : (t == 1 ? 1 : 2));
    }
}